// Round 12
// baseline (94.936 us; speedup 1.0000x reference)
//
#include <hip/hip_runtime.h>
#include <math.h>

// Shapelet distance + softmin pooling — MFMA version, INSTRUMENTED.
// x: (8, 8, 2048) f32, w: (32, 8, 32) f32
// out: [pred (8*256), d_min (8*256)] f32
//
// ROUND 12 = MEASUREMENT: round 11's MFMA kernel is ~7.7us vs ~2us model,
// invisible in the profile (top-5 = 38-40us harness fills). Repeat the
// MFMA+softmin region 32x (identical result each repeat; opaque SGPR zero
// in the LDS address defeats CSE/hoist of raceless LDS reads; per-repeat
// keep-alive asm defeats DCE) -> dispatch ~50-100us = top-1 with counters.
// waves_per_eu(2,2): rule out staging spills (1 block/CU -> 2 waves/SIMD).
// dur = ~6us + 32*L. L~3us+low VALU -> LDS-pipe-bound; L~1.3us+low busy ->
// latency-bound; VALUBusy>70% -> epilogue-bound.

#define T_VALID 2017
#define K10 14.426950408889634f   // 10/ln2: exp(10*z) == exp2(K10*z)
#define BIG 1e30f
#define REPEATS 32

typedef __attribute__((ext_vector_type(8))) short bf16x8;
typedef __attribute__((ext_vector_type(4))) float f32x4;

union FragU { unsigned u[4]; bf16x8 v; };

__device__ __forceinline__ float fexp2(float v) {
    float r; asm("v_exp_f32 %0, %1" : "=v"(r) : "v"(v)); return r;
}
__device__ __forceinline__ unsigned cvtpk(float lo, float hi) {
    unsigned r; asm("v_cvt_pk_bf16_f32 %0, %1, %2" : "=v"(r) : "v"(lo), "v"(hi)); return r;
}
__device__ __forceinline__ void lse_merge(float& fm, float& fS, float om, float oS) {
    float nm = fminf(fm, om);
    fS = fmaf(fS, fexp2(K10 * (nm - fm)), oS * fexp2(K10 * (nm - om)));
    fm = nm;
}

__global__ __launch_bounds__(512)
__attribute__((amdgpu_waves_per_eu(2, 2)))
void shapelet_mfma(
    const float* __restrict__ x,
    const float* __restrict__ w,
    float* __restrict__ out)
{
    __shared__ float xl[2048];          // x row, f32
    __shared__ float ssl[2048];         // ss(t), BIG for t >= 2017
    __shared__ float pmw[8][16], pSw[8][16];

    const int bid = blockIdx.x;         // 128 = b(8) * m(8) * ntile(2)
    const int b = bid >> 4;
    const int m = (bid >> 1) & 7;
    const int ntile = bid & 1;
    const int tid = threadIdx.x;        // 0..511
    const int lane = tid & 63;
    const int wv = tid >> 6;            // wave 0..7
    const int r = lane & 15;            // A-row / B-col within tile
    const int q = lane >> 4;            // k-group 0..3

    const float* xr = x + (((b << 3) + m) << 11);   // 2048 f32

    // ---- stage x row + masked sliding ss (thread: t = 4*tid .. 4*tid+3)
    {
        const float4* x4g = (const float4*)xr;
        const int t0 = tid << 2;
        float xs[36];
        #pragma unroll
        for (int jj = 0; jj < 9; ++jj) {
            int idx = tid + jj;
            idx = idx > 511 ? 511 : idx;    // clamp: garbage only feeds masked t
            const float4 v = x4g[idx];
            xs[4 * jj + 0] = v.x; xs[4 * jj + 1] = v.y;
            xs[4 * jj + 2] = v.z; xs[4 * jj + 3] = v.w;
            if (jj == 0) *(float4*)&xl[t0] = v;   // own (unclamped) chunk
        }
        float sv0 = 0.0f;
        #pragma unroll
        for (int l = 0; l < 32; ++l) sv0 = fmaf(xs[l], xs[l], sv0);
        float sv[4];
        sv[0] = sv0;
        #pragma unroll
        for (int i = 1; i < 4; ++i)
            sv[i] = fmaf(xs[31 + i], xs[31 + i], sv[i - 1]) - xs[i - 1] * xs[i - 1];
        #pragma unroll
        for (int i = 0; i < 4; ++i)
            if (t0 + i >= T_VALID) sv[i] = BIG;   // auto-masks d2 downstream
        f32x4 s4 = {sv[0], sv[1], sv[2], sv[3]};
        *(f32x4*)&ssl[t0] = s4;
    }

    // ---- per-lane: exact w2 (f32) + B-fragment (bf16), n = ntile*16 + r
    const int n = (ntile << 4) + r;
    const float* wrow = w + (((n << 3) + m) << 5);
    float w2v = 0.0f;
    #pragma unroll
    for (int l = 0; l < 32; ++l) w2v = fmaf(wrow[l], wrow[l], w2v);
    FragU bf;
    #pragma unroll
    for (int p = 0; p < 4; ++p)
        bf.u[p] = cvtpk(wrow[(q << 3) + 2 * p], wrow[(q << 3) + 2 * p + 1]);

    __syncthreads();

    // opaque zero: prevents CSE/hoist of LDS reads across repeats
    int zero;
    asm volatile("s_mov_b32 %0, 0" : "=s"(zero));

    // ---- MFMA loop, repeated 32x for instrumentation
    float mr = BIG, S = 0.0f;
    #pragma unroll 1
    for (int rep = 0; rep < REPEATS; ++rep) {
        mr = BIG; S = 0.0f;
        #pragma unroll 4
        for (int i = 0; i < 16; ++i) {
            const int tt = (wv << 4) + i;
            int base = (tt << 4) + r + (q << 3) + zero;   // A[r][8q+j] = x[16tt+r+8q+j]
            base = base > 2040 ? 2040 : base;             // exact: preserves valid t
            FragU af;
            #pragma unroll
            for (int p = 0; p < 4; ++p)
                af.u[p] = cvtpk(xl[base + 2 * p], xl[base + 2 * p + 1]);
            f32x4 acc = {0.0f, 0.0f, 0.0f, 0.0f};
            acc = __builtin_amdgcn_mfma_f32_16x16x32_bf16(af.v, bf.v, acc, 0, 0, 0);
            // C: col = lane&15 (=n), row = 4q + j  ->  t = 16tt + 4q + j
            const f32x4 sv = *(const f32x4*)&ssl[(tt << 4) + (q << 2)];
            const float d0 = fmaf(-2.0f, acc[0], sv[0] + w2v);
            const float d1 = fmaf(-2.0f, acc[1], sv[1] + w2v);
            const float d2_ = fmaf(-2.0f, acc[2], sv[2] + w2v);
            const float d3 = fmaf(-2.0f, acc[3], sv[3] + w2v);
            const float tmin = fminf(fminf(d0, d1), fminf(d2_, d3));
            const float nm = fminf(mr, tmin);
            const float st = fexp2(K10 * (nm - d0)) + fexp2(K10 * (nm - d1))
                           + fexp2(K10 * (nm - d2_)) + fexp2(K10 * (nm - d3));
            S = fmaf(S, fexp2(K10 * (nm - mr)), st);
            mr = nm;
        }
        asm volatile("" :: "v"(mr), "v"(S));   // keep each repeat live
    }

    // ---- merge the 4 k-groups (rows partition): lanes with same r
    #pragma unroll
    for (int off = 16; off <= 32; off <<= 1) {
        const float om = __shfl_xor(mr, off);
        const float oS = __shfl_xor(S, off);
        lse_merge(mr, S, om, oS);
    }
    if (lane < 16) { pmw[wv][lane] = mr; pSw[wv][lane] = S; }
    __syncthreads();

    // ---- merge 8 waves (t-chunks) and write
    if (tid < 16) {
        float fm = pmw[0][tid], fS = pSw[0][tid];
        #pragma unroll
        for (int wq = 1; wq < 8; ++wq)
            lse_merge(fm, fS, pmw[wq][tid], pSw[wq][tid]);
        const int no = (ntile << 4) + tid;
        const int o = (b << 8) + (no << 3) + m;
        out[o]        = expf(-fm + 0.1f * logf(fS));
        out[2048 + o] = sqrtf(fmaxf(fm, 0.0f));
    }
}

extern "C" void kernel_launch(void* const* d_in, const int* in_sizes, int n_in,
                              void* d_out, int out_size, void* d_ws, size_t ws_size,
                              hipStream_t stream) {
    const float* x = (const float*)d_in[0];   // (8,8,2048)
    const float* w = (const float*)d_in[1];   // (32,8,32)
    float* out = (float*)d_out;               // 4096 floats
    hipLaunchKernelGGL(shapelet_mfma, dim3(128), dim3(512), 0, stream, x, w, out);
}

// Round 13
// 15.093 us; speedup vs baseline: 6.2901x; 6.2901x over previous
//
#include <hip/hip_runtime.h>
#include <math.h>

// Shapelet distance + softmin pooling — MFMA, phase-split, full-GPU.
// x: (8, 8, 2048) f32, w: (32, 8, 32) f32
// out: [pred (8*256), d_min (8*256)] f32
//
// d2(b,t,n,m) = ss(t) + w2(n,m) - 2*dot(t,n)  [ss,w2 exact f32; dot bf16 MFMA]
// Round 13: round 12 counters (L=2.8us, VALUBusy 38%, MfmaUtil 3.4%, 0 bank
// conflicts, occ 11%) => dependency-latency-bound. Fixes: (1) phase-split
// softmin: d2 -> regs, global-min first, then independent exps (no serial
// rescale chain); (2) parity-interleaved packed-bf16 LDS: A-frag = 4
// ds_read_b32, shared across BOTH n-tiles (2 MFMA per frag); (3) 256 blocks
// (b,m,t-quarter) -> all CUs; tiny combine kernel merges 4 partials.

#define T_VALID 2017
#define K10 14.426950408889634f   // 10/ln2: exp(10*z) == exp2(K10*z)
#define BIG 1e30f

typedef __attribute__((ext_vector_type(8))) short bf16x8;
typedef __attribute__((ext_vector_type(4))) float f32x4;

union FragU { unsigned u[4]; bf16x8 v; };

__device__ __forceinline__ float fexp2(float v) {
    float r; asm("v_exp_f32 %0, %1" : "=v"(r) : "v"(v)); return r;
}
__device__ __forceinline__ unsigned cvtpk(float lo, float hi) {
    unsigned r; asm("v_cvt_pk_bf16_f32 %0, %1, %2" : "=v"(r) : "v"(lo), "v"(hi)); return r;
}
__device__ __forceinline__ void lse_merge(float& fm, float& fS, float om, float oS) {
    float nm = fminf(fm, om);
    fS = fmaf(fS, fexp2(K10 * (nm - fm)), oS * fexp2(K10 * (nm - om)));
    fm = nm;
}

__global__ __launch_bounds__(512)
__attribute__((amdgpu_waves_per_eu(2, 2)))
void shapelet_mfma(
    const float* __restrict__ x,
    const float* __restrict__ w,
    float* __restrict__ ws)
{
    __shared__ unsigned xp[4096];      // parity-interleaved bf16 pairs of x row
    __shared__ float ssl[2048];        // ss(t), BIG for t >= 2017
    __shared__ float red[8][2][16];    // per-wave partial (min, then S)
    __shared__ float gmin[2][16];      // block-global min per (ntile, n)

    const int bid = blockIdx.x;        // 256 = b(8) * m(8) * th(4)
    const int b  = bid >> 5;
    const int m  = (bid >> 2) & 7;
    const int th = bid & 3;            // t-quarter (512 t)
    const int tid = threadIdx.x;       // 0..511
    const int lane = tid & 63;
    const int wv = tid >> 6;           // wave 0..7
    const int r = lane & 15;           // A-row / B-col in tile
    const int q = lane >> 4;           // k-group 0..3

    const float* xr = x + (((b << 3) + m) << 11);   // 2048 f32

    // ---- stage packed x pairs: xp[2i]=(x2i,x2i+1), xp[2i+1]=(x2i+1,x2i+2)
    {
        const float4 v = ((const float4*)xr)[tid];
        const int nx = (tid << 2) + 4;
        const float nxt = xr[nx > 2047 ? 2047 : nx];
        uint4 pk;
        pk.x = cvtpk(v.x, v.y);        // pair 2tid   (even)
        pk.y = cvtpk(v.y, v.z);        // pair 2tid   (odd)
        pk.z = cvtpk(v.z, v.w);        // pair 2tid+1 (even)
        pk.w = cvtpk(v.w, nxt);        // pair 2tid+1 (odd)
        *(uint4*)&xp[tid << 2] = pk;
    }
    // ---- stage masked sliding ss (thread: t = 4*tid .. 4*tid+3)
    {
        const float4* x4g = (const float4*)xr;
        const int t0 = tid << 2;
        float xs[36];
        #pragma unroll
        for (int jj = 0; jj < 9; ++jj) {
            int idx = tid + jj;
            idx = idx > 511 ? 511 : idx;
            const float4 v = x4g[idx];
            xs[4 * jj + 0] = v.x; xs[4 * jj + 1] = v.y;
            xs[4 * jj + 2] = v.z; xs[4 * jj + 3] = v.w;
        }
        float sv0 = 0.0f;
        #pragma unroll
        for (int l = 0; l < 32; ++l) sv0 = fmaf(xs[l], xs[l], sv0);
        float sv[4];
        sv[0] = sv0;
        #pragma unroll
        for (int i = 1; i < 4; ++i)
            sv[i] = fmaf(xs[31 + i], xs[31 + i], sv[i - 1]) - xs[i - 1] * xs[i - 1];
        #pragma unroll
        for (int i = 0; i < 4; ++i)
            if (t0 + i >= T_VALID) sv[i] = BIG;
        f32x4 s4 = {sv[0], sv[1], sv[2], sv[3]};
        *(f32x4*)&ssl[t0] = s4;
    }

    // ---- per-lane B-fragments + exact w2 for n0 = r and n1 = 16 + r
    FragU bf0, bf1;
    float w20 = 0.0f, w21 = 0.0f;
    {
        const float* w0 = w + (((r << 3) + m) << 5);
        const float* w1 = w + ((((16 + r) << 3) + m) << 5);
        #pragma unroll
        for (int l = 0; l < 32; ++l) w20 = fmaf(w0[l], w0[l], w20);
        #pragma unroll
        for (int l = 0; l < 32; ++l) w21 = fmaf(w1[l], w1[l], w21);
        #pragma unroll
        for (int p = 0; p < 4; ++p) {
            bf0.u[p] = cvtpk(w0[(q << 3) + 2 * p], w0[(q << 3) + 2 * p + 1]);
            bf1.u[p] = cvtpk(w1[(q << 3) + 2 * p], w1[(q << 3) + 2 * p + 1]);
        }
    }

    __syncthreads();

    // ---- Phase A: 4 iters, each: 1 A-frag (4 ds_read_b32) -> 2 MFMA -> d2 regs
    float dA[16], dB[16];
    #pragma unroll
    for (int i = 0; i < 4; ++i) {
        const int tt = (th << 5) + (wv << 2) + i;    // t-tile 0..127
        int b0 = (tt << 4) + r + (q << 3);           // window element index
        b0 = b0 > 2040 ? 2040 : b0;                  // clamp (masked rows only)
        FragU af;
        #pragma unroll
        for (int p = 0; p < 4; ++p)
            af.u[p] = xp[b0 + 2 * p];                // parity-correct packed pair
        f32x4 z = {0.0f, 0.0f, 0.0f, 0.0f};
        const f32x4 a0 = __builtin_amdgcn_mfma_f32_16x16x32_bf16(af.v, bf0.v, z, 0, 0, 0);
        const f32x4 a1 = __builtin_amdgcn_mfma_f32_16x16x32_bf16(af.v, bf1.v, z, 0, 0, 0);
        const f32x4 sv = *(const f32x4*)&ssl[(tt << 4) + (q << 2)];
        #pragma unroll
        for (int j = 0; j < 4; ++j) {
            dA[4 * i + j] = fmaf(-2.0f, a0[j], sv[j] + w20);
            dB[4 * i + j] = fmaf(-2.0f, a1[j], sv[j] + w21);
        }
    }

    // ---- Phase B: block-global min per (ntile, n)
    float m0 = dA[0], m1 = dB[0];
    #pragma unroll
    for (int k = 1; k < 16; ++k) { m0 = fminf(m0, dA[k]); m1 = fminf(m1, dB[k]); }
    #pragma unroll
    for (int off = 16; off <= 32; off <<= 1) {
        m0 = fminf(m0, __shfl_xor(m0, off));
        m1 = fminf(m1, __shfl_xor(m1, off));
    }
    if (lane < 16) { red[wv][0][r] = m0; red[wv][1][r] = m1; }
    __syncthreads();
    if (tid < 32) {
        const int nt = tid >> 4, rr = tid & 15;
        float g = red[0][nt][rr];
        #pragma unroll
        for (int wq = 1; wq < 8; ++wq) g = fminf(g, red[wq][nt][rr]);
        gmin[nt][rr] = g;
    }
    __syncthreads();

    // ---- Phase C: independent exps vs global min, 4-way accumulators
    const float g0 = gmin[0][r], g1 = gmin[1][r];
    float sa0 = 0.0f, sa1 = 0.0f, sa2 = 0.0f, sa3 = 0.0f;
    float sb0 = 0.0f, sb1 = 0.0f, sb2 = 0.0f, sb3 = 0.0f;
    #pragma unroll
    for (int k = 0; k < 16; k += 4) {
        sa0 += fexp2(K10 * (g0 - dA[k]));     sa1 += fexp2(K10 * (g0 - dA[k + 1]));
        sa2 += fexp2(K10 * (g0 - dA[k + 2])); sa3 += fexp2(K10 * (g0 - dA[k + 3]));
        sb0 += fexp2(K10 * (g1 - dB[k]));     sb1 += fexp2(K10 * (g1 - dB[k + 1]));
        sb2 += fexp2(K10 * (g1 - dB[k + 2])); sb3 += fexp2(K10 * (g1 - dB[k + 3]));
    }
    float S0 = (sa0 + sa1) + (sa2 + sa3);
    float S1 = (sb0 + sb1) + (sb2 + sb3);
    #pragma unroll
    for (int off = 16; off <= 32; off <<= 1) {
        S0 += __shfl_xor(S0, off);
        S1 += __shfl_xor(S1, off);
    }
    __syncthreads();                       // red reuse: min values consumed
    if (lane < 16) { red[wv][0][r] = S0; red[wv][1][r] = S1; }
    __syncthreads();

    // ---- write per-(block) partials: gmin + summed S
    if (tid < 32) {
        const int nt = tid >> 4, rr = tid & 15;
        float Ssum = red[0][nt][rr];
        #pragma unroll
        for (int wq = 1; wq < 8; ++wq) Ssum += red[wq][nt][rr];
        const int base = ((((b << 3) + m) << 2) + th) << 5;   // *32
        ws[base + tid] = gmin[nt][rr];
        ws[8192 + base + tid] = Ssum;
    }
}

__global__ __launch_bounds__(256) void shapelet_combine(
    const float* __restrict__ ws,
    float* __restrict__ out)
{
    const int o = blockIdx.x * 256 + threadIdx.x;   // 0..2047
    const int b = o >> 8;
    const int rem = o & 255;
    const int n = rem >> 3;       // 0..31 (nt*16 + rr)
    const int m = rem & 7;

    const int bm = (((b << 3) + m) << 2);
    float fm = ws[(bm << 5) + n], fS = ws[8192 + (bm << 5) + n];
    #pragma unroll
    for (int th = 1; th < 4; ++th) {
        const int base = (bm + th) << 5;
        lse_merge(fm, fS, ws[base + n], ws[8192 + base + n]);
    }
    out[o]        = expf(-fm + 0.1f * logf(fS));
    out[2048 + o] = sqrtf(fmaxf(fm, 0.0f));
}

extern "C" void kernel_launch(void* const* d_in, const int* in_sizes, int n_in,
                              void* d_out, int out_size, void* d_ws, size_t ws_size,
                              hipStream_t stream) {
    const float* x = (const float*)d_in[0];   // (8,8,2048)
    const float* w = (const float*)d_in[1];   // (32,8,32)
    float* out = (float*)d_out;               // 4096 floats
    float* ws  = (float*)d_ws;                // 16384 floats used
    hipLaunchKernelGGL(shapelet_mfma,    dim3(256), dim3(512), 0, stream, x, w, ws);
    hipLaunchKernelGGL(shapelet_combine, dim3(8),   dim3(256), 0, stream, ws, out);
}

// Round 14
// 10.028 us; speedup vs baseline: 9.4670x; 1.5051x over previous
//
#include <hip/hip_runtime.h>
#include <math.h>

// Shapelet distance + softmin pooling — MFMA, single kernel, lean prologue.
// x: (8, 8, 2048) f32, w: (32, 8, 32) f32
// out: [pred (8*256), d_min (8*256)] f32
//
// d2(b,t,n,m) = ss(t) + w2(n,m) - 2*dot(t,n)  [ss,w2 exact f32; dot bf16 MFMA]
// Round 14: R12 arithmetic: kernel = base(6.3us!) + inner(2.8us). Base was
// per-lane w scalar loads (128) + double x staging; inner was ds_read_b32
// frag gather + serial softmin. Fixes: (1) w: 2 dwordx4/lane + shfl-reduced
// w2; (2) A-frag = ONE ds_read_b128 from 8-shift bf16 chunk store (row pad
// 257 -> bank-optimal); (3) phase-split min/exp (no serial chain), all in
// ONE kernel (two-kernel designs lost ~3-4us: R10, R13).

#define T_VALID 2017
#define K10 14.426950408889634f   // 10/ln2: exp(10*z) == exp2(K10*z)
#define BIG 1e30f

typedef __attribute__((ext_vector_type(8))) short bf16x8;
typedef __attribute__((ext_vector_type(4))) float f32x4;

union FragU { unsigned u[4]; uint4 q; bf16x8 v; };

__device__ __forceinline__ float fexp2(float v) {
    float r; asm("v_exp_f32 %0, %1" : "=v"(r) : "v"(v)); return r;
}
__device__ __forceinline__ unsigned cvtpk(float lo, float hi) {
    unsigned r; asm("v_cvt_pk_bf16_f32 %0, %1, %2" : "=v"(r) : "v"(lo), "v"(hi)); return r;
}

__global__ __launch_bounds__(512)
__attribute__((amdgpu_waves_per_eu(2, 2)))
void shapelet_mfma(
    const float* __restrict__ x,
    const float* __restrict__ w,
    float* __restrict__ out)
{
    // 8-shift chunk store: xs8[s*257+i] (16B) = bf16 x[8i+s .. 8i+s+7].
    // Window start b0 -> one aligned ds_read_b128 at (s=b0&7, i=b0>>3).
    __shared__ unsigned xs8[8 * 257 * 4];   // 32.9 KB
    __shared__ float ssl[2048];             // ss(t), BIG for t >= T_VALID
    __shared__ float red[8][16];
    __shared__ float gml[16];

    const int bid = blockIdx.x;         // 128 = b(8) * m(8) * ntile(2)
    const int b = bid >> 4;
    const int m = (bid >> 1) & 7;
    const int ntile = bid & 1;
    const int tid = threadIdx.x;        // 0..511
    const int lane = tid & 63;
    const int wv = tid >> 6;            // wave 0..7
    const int r = lane & 15;            // B-col (n within tile) / A-row
    const int q = lane >> 4;            // k-group 0..3

    const float* xr = x + (((b << 3) + m) << 11);   // 2048 f32

    // ---- w: lane loads ONLY its frag slice (2 dwordx4); w2 via shfl reduce
    const int n = (ntile << 4) + r;
    const float* wrow = w + (((n << 3) + m) << 5);
    const float4 f0 = ((const float4*)wrow)[(q << 1)];
    const float4 f1 = ((const float4*)wrow)[(q << 1) + 1];

    // ---- stage x: window regs -> ss + 8-shift bf16 chunks
    {
        const float4* x4g = (const float4*)xr;
        float xs[36];
        #pragma unroll
        for (int jj = 0; jj < 9; ++jj) {
            int idx = tid + jj;
            idx = idx > 511 ? 511 : idx;      // clamp: feeds only masked t
            const float4 v = x4g[idx];
            xs[4 * jj + 0] = v.x; xs[4 * jj + 1] = v.y;
            xs[4 * jj + 2] = v.z; xs[4 * jj + 3] = v.w;
        }
        // chunks p = 4*tid+k: bf16 x[p..p+7] -> row p&7, col p>>3
        #pragma unroll
        for (int k = 0; k < 4; ++k) {
            const int p = (tid << 2) + k;
            FragU ch;
            ch.u[0] = cvtpk(xs[k + 0], xs[k + 1]);
            ch.u[1] = cvtpk(xs[k + 2], xs[k + 3]);
            ch.u[2] = cvtpk(xs[k + 4], xs[k + 5]);
            ch.u[3] = cvtpk(xs[k + 6], xs[k + 7]);
            *(uint4*)&xs8[((p & 7) * 257 + (p >> 3)) << 2] = ch.q;
        }
        // sliding ss for t = 4*tid .. 4*tid+3, masked tail -> BIG
        float sv0 = 0.0f;
        #pragma unroll
        for (int l = 0; l < 32; ++l) sv0 = fmaf(xs[l], xs[l], sv0);
        float sv[4];
        sv[0] = sv0;
        #pragma unroll
        for (int i = 1; i < 4; ++i)
            sv[i] = fmaf(xs[31 + i], xs[31 + i], sv[i - 1]) - xs[i - 1] * xs[i - 1];
        const int t0 = tid << 2;
        #pragma unroll
        for (int i = 0; i < 4; ++i)
            if (t0 + i >= T_VALID) sv[i] = BIG;
        f32x4 s4 = {sv[0], sv[1], sv[2], sv[3]};
        *(f32x4*)&ssl[t0] = s4;
    }

    // ---- B-frag + shfl-reduced w2 (lanes with same r share n)
    FragU bf;
    bf.u[0] = cvtpk(f0.x, f0.y); bf.u[1] = cvtpk(f0.z, f0.w);
    bf.u[2] = cvtpk(f1.x, f1.y); bf.u[3] = cvtpk(f1.z, f1.w);
    float w2v = f0.x * f0.x;
    w2v = fmaf(f0.y, f0.y, w2v); w2v = fmaf(f0.z, f0.z, w2v);
    w2v = fmaf(f0.w, f0.w, w2v); w2v = fmaf(f1.x, f1.x, w2v);
    w2v = fmaf(f1.y, f1.y, w2v); w2v = fmaf(f1.z, f1.z, w2v);
    w2v = fmaf(f1.w, f1.w, w2v);
    w2v += __shfl_xor(w2v, 16);
    w2v += __shfl_xor(w2v, 32);

    __syncthreads();

    // ---- Phase A: 16 independent {b128 A-frag -> MFMA -> d2 regs}
    float dA[64];
    #pragma unroll
    for (int i = 0; i < 16; ++i) {
        const int tt = (wv << 4) + i;               // t-tile 0..127
        int b0 = (tt << 4) + r + (q << 3);          // window start
        b0 = b0 > 2040 ? 2040 : b0;                 // clamp (masked rows only)
        FragU af;
        af.q = *(const uint4*)&xs8[((b0 & 7) * 257 + (b0 >> 3)) << 2];
        f32x4 z = {0.0f, 0.0f, 0.0f, 0.0f};
        const f32x4 acc = __builtin_amdgcn_mfma_f32_16x16x32_bf16(af.v, bf.v, z, 0, 0, 0);
        // C: col = lane&15 (=n), row = 4q + j -> t = 16tt + 4q + j
        const f32x4 sv = *(const f32x4*)&ssl[(tt << 4) + (q << 2)];
        dA[4 * i + 0] = fmaf(-2.0f, acc[0], sv[0] + w2v);
        dA[4 * i + 1] = fmaf(-2.0f, acc[1], sv[1] + w2v);
        dA[4 * i + 2] = fmaf(-2.0f, acc[2], sv[2] + w2v);
        dA[4 * i + 3] = fmaf(-2.0f, acc[3], sv[3] + w2v);
    }

    // ---- Phase B: block-global min per n
    float m0 = dA[0];
    #pragma unroll
    for (int k = 1; k < 64; ++k) m0 = fminf(m0, dA[k]);
    m0 = fminf(m0, __shfl_xor(m0, 16));
    m0 = fminf(m0, __shfl_xor(m0, 32));
    if (lane < 16) red[wv][r] = m0;
    __syncthreads();
    if (tid < 16) {
        float g = red[0][tid];
        #pragma unroll
        for (int wq = 1; wq < 8; ++wq) g = fminf(g, red[wq][tid]);
        gml[tid] = g;
    }
    __syncthreads();

    // ---- Phase C: 64 independent exps vs global min, 4-way accumulators
    const float g0 = gml[r];
    float sa0 = 0.0f, sa1 = 0.0f, sa2 = 0.0f, sa3 = 0.0f;
    #pragma unroll
    for (int k = 0; k < 64; k += 4) {
        sa0 += fexp2(K10 * (g0 - dA[k + 0]));
        sa1 += fexp2(K10 * (g0 - dA[k + 1]));
        sa2 += fexp2(K10 * (g0 - dA[k + 2]));
        sa3 += fexp2(K10 * (g0 - dA[k + 3]));
    }
    float S = (sa0 + sa1) + (sa2 + sa3);
    S += __shfl_xor(S, 16);
    S += __shfl_xor(S, 32);
    if (lane < 16) red[wv][r] = S;
    __syncthreads();

    // ---- final: sum 8 wave partials, write pred + dmin
    if (tid < 16) {
        float Ssum = red[0][tid];
        #pragma unroll
        for (int wq = 1; wq < 8; ++wq) Ssum += red[wq][tid];
        const float g = gml[tid];
        const int o = (b << 8) + (((ntile << 4) + tid) << 3) + m;
        out[o]        = expf(-g + 0.1f * logf(Ssum));
        out[2048 + o] = sqrtf(fmaxf(g, 0.0f));
    }
}

extern "C" void kernel_launch(void* const* d_in, const int* in_sizes, int n_in,
                              void* d_out, int out_size, void* d_ws, size_t ws_size,
                              hipStream_t stream) {
    const float* x = (const float*)d_in[0];   // (8,8,2048)
    const float* w = (const float*)d_in[1];   // (32,8,32)
    float* out = (float*)d_out;               // 4096 floats
    hipLaunchKernelGGL(shapelet_mfma, dim3(128), dim3(512), 0, stream, x, w, out);
}